// Round 1
// baseline (364.492 us; speedup 1.0000x reference)
//
#include <hip/hip_runtime.h>

// Equivariant linear: segments (u,i) = (64,1),(32,3),(16,5); in==out, 240 cols.
// o[n,v,i] = (1/sqrt(u)) * sum_u x[n,u,i] * w[u,v], per segment.
//
// R1: latency-bound fix. Weights no longer staged in LDS (L1-resident global
// loads instead: all blocks read the same 21.5 KB). LDS = 30720 B -> 5
// blocks/CU (was 3 @ 52224 B). All LDS regions are wave-private (each wave
// owns 8 rows), so BOTH __syncthreads() are removed; waves stream
// load->compute->store independently, overlapping phases across 20 waves/CU.

#define TILE 32
#define BLOCK 256

__global__ __launch_bounds__(BLOCK, 5) void eqlin_kernel(
    const float* __restrict__ x, const float* __restrict__ w,
    float* __restrict__ out, int nrows)
{
    __shared__ __align__(16) float xs[TILE * 240];   // 30720 B only

    const int tid  = threadIdx.x;
    const int lane = tid & 63;
    const int wvid = tid >> 6;       // wave 0..3
    const int rb   = wvid * 8;       // this wave's 8 private rows
    const long long row0 = (long long)blockIdx.x * TILE;

    // ---- stage this wave's 8 rows (480 float4), fully coalesced ----
    {
        const float4* __restrict__ xg = (const float4*)(x + (row0 + rb) * 240);
        float4* xl = (float4*)(xs + rb * 240);
        #pragma unroll
        for (int j = 0; j < 7; ++j) xl[j * 64 + lane] = xg[j * 64 + lane];
        if (lane < 32) xl[448 + lane] = xg[448 + lane];   // 480 = 7*64 + 32
    }
    // wave-private data + wave lockstep: no __syncthreads needed anywhere.
    __builtin_amdgcn_wave_barrier();   // compiler ordering fence (no HW cost)

    // ================= segment 0: u=v=64, i=1, cols [0,64) =================
    {
        const int v = lane;                   // lane-consecutive weight reads
        float acc[8];
        #pragma unroll
        for (int r = 0; r < 8; ++r) acc[r] = 0.f;
        #pragma unroll 4
        for (int k = 0; k < 16; ++k) {        // u in groups of 4
            const float w0 = w[(4*k+0)*64 + v];   // 256B-coalesced, L1-hit
            const float w1 = w[(4*k+1)*64 + v];
            const float w2 = w[(4*k+2)*64 + v];
            const float w3 = w[(4*k+3)*64 + v];
            #pragma unroll
            for (int r = 0; r < 8; ++r) {
                const float4 xq = *(const float4*)&xs[(rb + r)*240 + 4*k]; // wave-broadcast
                acc[r] += xq.x*w0 + xq.y*w1 + xq.z*w2 + xq.w*w3;
            }
        }
        // in-place writeback (all reads of this region done; wave-private rows)
        #pragma unroll
        for (int r = 0; r < 8; ++r) xs[(rb + r)*240 + v] = acc[r] * 0.125f;
    }

    // ================= segment 1: u=v=32, i=3, cols [64,160) =================
    {
        const int v  = lane & 31;
        const int h  = lane >> 5;             // half-wave -> row subset
        const int r0 = rb + h * 4;            // 4 rows per lane
        const float* __restrict__ w1p = w + 4096;
        float acc[4][3];
        #pragma unroll
        for (int r = 0; r < 4; ++r)
            #pragma unroll
            for (int i = 0; i < 3; ++i) acc[r][i] = 0.f;
        #pragma unroll 4
        for (int k = 0; k < 8; ++k) {         // u in groups of 4 -> 12 contiguous floats
            const float w0 = w1p[(4*k+0)*32 + v];
            const float w1 = w1p[(4*k+1)*32 + v];
            const float w2 = w1p[(4*k+2)*32 + v];
            const float w3 = w1p[(4*k+3)*32 + v];
            #pragma unroll
            for (int r = 0; r < 4; ++r) {
                const float* xr = &xs[(r0 + r)*240 + 64 + 12*k];
                const float4 a = *(const float4*)(xr);       // (du,i): 00 01 02 10
                const float4 b = *(const float4*)(xr + 4);   // 11 12 20 21
                const float4 c = *(const float4*)(xr + 8);   // 22 30 31 32
                acc[r][0] += a.x*w0 + a.w*w1 + b.z*w2 + c.y*w3;
                acc[r][1] += a.y*w0 + b.x*w1 + b.w*w2 + c.z*w3;
                acc[r][2] += a.z*w0 + b.y*w1 + c.x*w2 + c.w*w3;
            }
        }
        const float s1 = 0.17677669529663687f;   // 1/sqrt(32)
        #pragma unroll
        for (int r = 0; r < 4; ++r)
            #pragma unroll
            for (int i = 0; i < 3; ++i)
                xs[(r0 + r)*240 + 64 + v*3 + i] = acc[r][i] * s1;
    }

    // ================= segment 2: u=v=16, i=5, cols [160,240) =================
    {
        const int v  = lane & 15;
        const int q  = lane >> 4;             // quarter-wave -> row subset
        const int r0 = rb + q * 2;            // 2 rows per lane
        const float* __restrict__ w2p = w + 5120;
        float acc[2][5];
        #pragma unroll
        for (int r = 0; r < 2; ++r)
            #pragma unroll
            for (int i = 0; i < 5; ++i) acc[r][i] = 0.f;
        #pragma unroll
        for (int k = 0; k < 4; ++k) {         // u in groups of 4 -> 20 contiguous floats
            const float w0 = w2p[(4*k+0)*16 + v];
            const float w1 = w2p[(4*k+1)*16 + v];
            const float w2 = w2p[(4*k+2)*16 + v];
            const float w3 = w2p[(4*k+3)*16 + v];
            #pragma unroll
            for (int r = 0; r < 2; ++r) {
                const float* xr = &xs[(r0 + r)*240 + 160 + 20*k];
                const float4 a = *(const float4*)(xr);       // idx 0..3
                const float4 b = *(const float4*)(xr + 4);   // 4..7
                const float4 c = *(const float4*)(xr + 8);   // 8..11
                const float4 d = *(const float4*)(xr + 12);  // 12..15
                const float4 e = *(const float4*)(xr + 16);  // 16..19
                acc[r][0] += a.x*w0 + b.y*w1 + c.z*w2 + d.w*w3;  // idx 0,5,10,15
                acc[r][1] += a.y*w0 + b.z*w1 + c.w*w2 + e.x*w3;  // 1,6,11,16
                acc[r][2] += a.z*w0 + b.w*w1 + d.x*w2 + e.y*w3;  // 2,7,12,17
                acc[r][3] += a.w*w0 + c.x*w1 + d.y*w2 + e.z*w3;  // 3,8,13,18
                acc[r][4] += b.x*w0 + c.y*w1 + d.z*w2 + e.w*w3;  // 4,9,14,19
            }
        }
        #pragma unroll
        for (int r = 0; r < 2; ++r)
            #pragma unroll
            for (int i = 0; i < 5; ++i)
                xs[(r0 + r)*240 + 160 + v*5 + i] = acc[r][i] * 0.25f;
    }

    __builtin_amdgcn_wave_barrier();   // ordering fence before bulk re-read

    // ---- wave-private coalesced bulk store of the transformed 8 rows ----
    {
        float4* og = (float4*)(out + (row0 + rb) * 240);
        const float4* xl = (const float4*)(xs + rb * 240);
        #pragma unroll
        for (int j = 0; j < 7; ++j) og[j * 64 + lane] = xl[j * 64 + lane];
        if (lane < 32) og[448 + lane] = xl[448 + lane];
    }
}

extern "C" void kernel_launch(void* const* d_in, const int* in_sizes, int n_in,
                              void* d_out, int out_size, void* d_ws, size_t ws_size,
                              hipStream_t stream) {
    const float* x = (const float*)d_in[0];
    const float* w = (const float*)d_in[1];
    float* out = (float*)d_out;
    const int nrows = in_sizes[0] / 240;          // 200000
    const int blocks = nrows / TILE;              // 6250 (exact)
    eqlin_kernel<<<blocks, BLOCK, 0, stream>>>(x, w, out, nrows);
}